// Round 7
// baseline (807.715 us; speedup 1.0000x reference)
//
#include <hip/hip_runtime.h>
#include <cstdint>
#include <cstddef>

#define NB 8
#define NPTS 8192
#define S_TOT 512
#define NSAMP 64
#define DFEAT 64
#define INCH 67
#define SLOTS 17
#define CCAP (SLOTS * 256)   // 4352 compacted slots per (b,grp)

typedef __attribute__((ext_vector_type(8))) short v8s;
typedef __attribute__((ext_vector_type(4))) short v4s;
typedef __attribute__((ext_vector_type(4))) float v4f;

// exact (numpy-matching) squared distance: (a-b) per component, square, sum as (x+y)+z
__device__ __forceinline__ float d2_exact(float ax, float ay, float az,
                                          float bx, float by, float bz) {
    float dx = __fsub_rn(ax, bx);
    float dy = __fsub_rn(ay, by);
    float dz = __fsub_rn(az, bz);
    return __fadd_rn(__fadd_rn(__fmul_rn(dx, dx), __fmul_rn(dy, dy)), __fmul_rn(dz, dz));
}

// fp32 -> bf16 round-to-nearest-even
__device__ __forceinline__ unsigned short f2b(float f) {
    unsigned u = __float_as_uint(f);
    return (unsigned short)((u + 0x7fffu + ((u >> 16) & 1u)) >> 16);
}

template <int CTRL>
__device__ __forceinline__ unsigned long long dpp_max_u64(unsigned long long k) {
    int lo = (int)(unsigned)(k & 0xffffffffull);
    int hi = (int)(unsigned)(k >> 32);
    int slo = __builtin_amdgcn_update_dpp(lo, lo, CTRL, 0xf, 0xf, false);
    int shi = __builtin_amdgcn_update_dpp(hi, hi, CTRL, 0xf, 0xf, false);
    unsigned long long o = ((unsigned long long)(unsigned)shi << 32) | (unsigned)slo;
    return (o > k) ? o : k;
}

// ---------------------------------------------------------------------------
// FPS stage 1 (unchanged, R5/R6-verified): compact + sort-preserving rep
// insertion. attention is 0/1 -> masked-out points are exactly (+/-0,+/-0,+/-0)
// with bit-identical min_d2 trajectories; collapse to one representative at
// the min masked index rm. Slot order == original index order.
// ---------------------------------------------------------------------------
__global__ __launch_bounds__(1024) void fps_compact(
    const float* __restrict__ xyz, const float* __restrict__ attn,
    float4* __restrict__ cxyz, int* __restrict__ hdr)
{
    int blk = blockIdx.x;
    int b = blk >> 1, grp = blk & 1;
    const float* xb = xyz + (size_t)b * 3 * NPTS;
    const float* ab = attn + (size_t)b * NPTS;
    float4* c4 = cxyz + (size_t)blk * CCAP;

    int tid = threadIdx.x, lane = tid & 63, wid = tid >> 6;
    int n0 = tid * 8;

    __shared__ int s_repmin;
    __shared__ int s_ws[16];
    if (tid == 0) s_repmin = NPTS;
    __syncthreads();

    float av[8];
    *(float4*)&av[0] = *(const float4*)(ab + n0);
    *(float4*)&av[4] = *(const float4*)(ab + n0 + 4);
    int cnt = 0, mymin = NPTS;
    bool keep[8];
#pragma unroll
    for (int j = 0; j < 8; j++) {
        keep[j] = grp ? (av[j] == 0.0f) : (av[j] != 0.0f);
        cnt += keep[j] ? 1 : 0;
        if (!keep[j] && n0 + j < mymin) mymin = n0 + j;
    }
    if (mymin < NPTS) atomicMin(&s_repmin, mymin);

    int incl = cnt;
#pragma unroll
    for (int off = 1; off <= 32; off <<= 1) {
        int t = __shfl_up(incl, off);
        if (lane >= off) incl += t;
    }
    if (lane == 63) s_ws[wid] = incl;
    __syncthreads();
    int woff = 0, tot = 0;
#pragma unroll
    for (int w = 0; w < 16; w++) { if (w < wid) woff += s_ws[w]; tot += s_ws[w]; }
    int pos = woff + incl - cnt;
    int rm = s_repmin;
    int rm_eff = (rm < NPTS) ? rm : 0x7fffffff;

    float xv[8], yv[8], zv[8];
    *(float4*)&xv[0] = *(const float4*)(xb + n0);
    *(float4*)&xv[4] = *(const float4*)(xb + n0 + 4);
    *(float4*)&yv[0] = *(const float4*)(xb + NPTS + n0);
    *(float4*)&yv[4] = *(const float4*)(xb + NPTS + n0 + 4);
    *(float4*)&zv[0] = *(const float4*)(xb + 2 * NPTS + n0);
    *(float4*)&zv[4] = *(const float4*)(xb + 2 * NPTS + n0 + 4);
#pragma unroll
    for (int j = 0; j < 8; j++) {
        if (keep[j]) {
            int fin = pos + ((n0 + j > rm_eff) ? 1 : 0);
            if (fin < CCAP)
                c4[fin] = make_float4(xv[j], yv[j], zv[j], 0.0f);
            pos++;
        }
    }
    if (tid == 0) {
        int M = tot;
        if (rm < NPTS) {
            if (rm < CCAP)
                c4[rm] = make_float4(__fmul_rn(0.0f, xb[rm]),
                                     __fmul_rn(0.0f, xb[NPTS + rm]),
                                     __fmul_rn(0.0f, xb[2 * NPTS + rm]), 0.0f);
            M++;
        }
        hdr[blk * 2] = M;
        hdr[blk * 2 + 1] = (rm < NPTS) ? rm : -1;
    }
}

// ---------------------------------------------------------------------------
// FPS stage 2 v4: 256 threads / 4 waves. Winner COORDS tracked through the
// argmax fold (+3 cndmask/slot) and shipped with the key: per iteration the
// serial chain is update -> DPP key max -> winner lane writes {key,coords}
// -> ONE barrier -> 8 broadcast reads issued back-to-back (ONE LDS latency
// window, was two serialized in R6) -> u64-max tree + cndmask coord select.
// The 68KB sc[] coord table is gone.
// ---------------------------------------------------------------------------
__global__ __launch_bounds__(256, 1) void fps_iter(
    const float* __restrict__ attn,
    const float4* __restrict__ cxyz,
    const int* __restrict__ hdr,
    float* __restrict__ out0, float* __restrict__ out2)
{
    int blk = blockIdx.x;
    int b = blk >> 1, grp = blk & 1;
    int K = grp ? 384 : 128;
    int soff = grp ? 128 : 0;
    int M = hdr[blk * 2];
    int repslot = hdr[blk * 2 + 1];
    if (M > CCAP) return;             // fps_kernel fallback covers this block
    int tid = threadIdx.x, wid = tid >> 6;

    const float4* cb = cxyz + (size_t)blk * CCAP;
    __shared__ __align__(16) unsigned long long s_key[2][4];
    __shared__ __align__(16) float4 s_co[2][4];
    __shared__ float4 s_obuf[384];

    // idle-wave safety: key 0 never wins; idle waves never write
    if (tid < 8) s_key[tid >> 2][tid & 3] = 0ull;

    float px[SLOTS], py[SLOTS], pz[SLOTS], md[SLOTS];
#pragma unroll
    for (int i = 0; i < SLOTS; i++) {
        int sl = i * 256 + tid;
        bool v = sl < M;
        float4 c = v ? cb[sl] : make_float4(0.f, 0.f, 0.f, 0.f);
        px[i] = c.x; py[i] = c.y; pz[i] = c.z;
        md[i] = v ? 1e10f : -1.0f;    // invalid: d2>=0 keeps -1, never beats valid
    }
    // slot 0 == original index 0 always (kept idx<rm at pos==idx; rm==0 -> rep at 0)
    float4 c0 = cb[0];
    float lx = c0.x, ly = c0.y, lz = c0.z;
    float a_last = attn[(size_t)b * NPTS];
    float kept_a = grp ? 0.0f : 1.0f;
    float rep_a  = grp ? 1.0f : 0.0f;

    for (int k = 0; k < K; k++) {
        if (tid == 0) s_obuf[k] = make_float4(lx, ly, lz, a_last);
        if (k == K - 1) break;

        // update + fold (value, slot, coords); ascending sl + explicit tiebreak
        // == numpy argmax first-occurrence (slot order == index order)
        float bv = -1.0f; int bslot = 0x7fffffff;
        float bx = 0.f, by = 0.f, bz = 0.f;
#pragma unroll
        for (int i = 0; i < SLOTS; i++) {
            float d2 = d2_exact(px[i], py[i], pz[i], lx, ly, lz);
            md[i] = fminf(md[i], d2);
            int sl = i * 256 + tid;
            bool w = (md[i] > bv) || ((md[i] == bv) && (sl < bslot));
            bv = w ? md[i] : bv;
            bslot = w ? sl : bslot;
            bx = w ? px[i] : bx;
            by = w ? py[i] : by;
            bz = w ? pz[i] : bz;
        }
        unsigned long long key = (bv >= 0.0f)
            ? (((unsigned long long)__float_as_uint(bv) << 32) | (unsigned)(~bslot))
            : 0ull;
        unsigned long long kmax = key;
        kmax = dpp_max_u64<0x111>(kmax);
        kmax = dpp_max_u64<0x112>(kmax);
        kmax = dpp_max_u64<0x114>(kmax);
        kmax = dpp_max_u64<0x118>(kmax);
        kmax = dpp_max_u64<0x142>(kmax);
        kmax = dpp_max_u64<0x143>(kmax);    // lane 63 = wave max
        unsigned wlo = (unsigned)__builtin_amdgcn_readlane((int)(unsigned)(kmax & 0xffffffffull), 63);
        unsigned whi = (unsigned)__builtin_amdgcn_readlane((int)(unsigned)(kmax >> 32), 63);
        unsigned long long wmax = ((unsigned long long)whi << 32) | wlo;
        int buf = k & 1;
        if (key == wmax && wmax != 0ull) {  // unique winner lane (slots unique)
            s_key[buf][wid] = wmax;
            s_co[buf][wid] = make_float4(bx, by, bz, 0.f);
        }
        __syncthreads();                    // lgkm-only drain (no global ops in flight)

        // all 8 broadcast reads back-to-back: one LDS latency window
        unsigned long long g0 = s_key[buf][0], g1 = s_key[buf][1];
        unsigned long long g2 = s_key[buf][2], g3 = s_key[buf][3];
        float4 r0 = s_co[buf][0], r1 = s_co[buf][1];
        float4 r2 = s_co[buf][2], r3 = s_co[buf][3];
        unsigned long long ga = (g0 > g1) ? g0 : g1;
        unsigned long long gb = (g2 > g3) ? g2 : g3;
        unsigned long long g  = (ga > gb) ? ga : gb;
        int ws = (int)(~(unsigned)g);       // winning slot
        int wv = (ws >> 6) & 3;             // winning wave (slot%256 = tid, tid>>6 = wave)
        float4 ra = (wv & 1) ? r1 : r0;
        float4 rb = (wv & 1) ? r3 : r2;
        float4 rc = (wv & 2) ? rb : ra;
        lx = rc.x; ly = rc.y; lz = rc.z;
        a_last = (ws == repslot) ? rep_a : kept_a;
    }
    __syncthreads();
    for (int k2 = tid; k2 < K; k2 += 256) {
        float4 o = s_obuf[k2];
        int sg = soff + k2;
        out0[(size_t)b * 3 * S_TOT + sg] = o.x;
        out0[(size_t)b * 3 * S_TOT + S_TOT + sg] = o.y;
        out0[(size_t)b * 3 * S_TOT + 2 * S_TOT + sg] = o.z;
        out2[(size_t)b * S_TOT + sg] = o.w;
    }
}

// ---------------------------------------------------------------------------
// Fallback FPS (unchanged): only if a block overflowed CCAP or ws too small.
// ---------------------------------------------------------------------------
__global__ __launch_bounds__(1024, 1) void fps_kernel(
    const float* __restrict__ xyz, const float* __restrict__ attn,
    const int* __restrict__ hdr,
    float* __restrict__ out0, float* __restrict__ out2)
{
    int blk = blockIdx.x;
    if (hdr != nullptr && hdr[blk * 2] <= CCAP) return;
    int b = blk >> 1, grp = blk & 1;
    int K = grp ? 384 : 128;
    int soff = grp ? 128 : 0;
    int tid = threadIdx.x, lane = tid & 63, wid = tid >> 6;
    const float* xb = xyz + (size_t)b * 3 * NPTS;
    const float* ab = attn + (size_t)b * NPTS;

    float px[8], py[8], pz[8], md[8];
#pragma unroll
    for (int i = 0; i < 8; i++) {
        int n = tid + i * 1024;
        float a = ab[n];
        float f = grp ? __fsub_rn(1.0f, a) : a;
        px[i] = __fmul_rn(f, xb[n]);
        py[i] = __fmul_rn(f, xb[NPTS + n]);
        pz[i] = __fmul_rn(f, xb[2 * NPTS + n]);
        md[i] = 1e10f;
    }
    __shared__ unsigned long long s_red[2][16];
    float a_last = ab[0];
    float f0 = grp ? __fsub_rn(1.0f, a_last) : a_last;
    float lx = __fmul_rn(f0, xb[0]);
    float ly = __fmul_rn(f0, xb[NPTS]);
    float lz = __fmul_rn(f0, xb[2 * NPTS]);

    for (int k = 0; k < K; k++) {
        if (tid == 0) {
            int sg = soff + k;
            out0[(size_t)b * 3 * S_TOT + sg] = lx;
            out0[(size_t)b * 3 * S_TOT + S_TOT + sg] = ly;
            out0[(size_t)b * 3 * S_TOT + 2 * S_TOT + sg] = lz;
            out2[(size_t)b * S_TOT + sg] = a_last;
        }
        if (k == K - 1) break;
        float bv = -1.0f; int bi = 0;
#pragma unroll
        for (int i = 0; i < 8; i++) {
            float d2 = d2_exact(px[i], py[i], pz[i], lx, ly, lz);
            md[i] = fminf(md[i], d2);
            if (md[i] > bv) { bv = md[i]; bi = tid + i * 1024; }
        }
        unsigned long long best =
            ((unsigned long long)__float_as_uint(bv) << 32) | (unsigned)(~bi);
#pragma unroll
        for (int off = 32; off >= 1; off >>= 1) {
            unsigned long long o = __shfl_down(best, off);
            best = (o > best) ? o : best;
        }
        if (lane == 0) s_red[k & 1][wid] = best;
        __syncthreads();
        unsigned long long r = (lane < 16) ? s_red[k & 1][lane] : 0ull;
#pragma unroll
        for (int off = 8; off >= 1; off >>= 1) {
            unsigned long long o = __shfl_down(r, off);
            r = (o > r) ? o : r;
        }
        r = __shfl(r, 0);
        int n = (int)(~(unsigned)r);
        a_last = ab[n];
        float fl = grp ? __fsub_rn(1.0f, a_last) : a_last;
        lx = __fmul_rn(fl, xb[n]);
        ly = __fmul_rn(fl, xb[NPTS + n]);
        lz = __fmul_rn(fl, xb[2 * NPTS + n]);
    }
}

// ---------------------------------------------------------------------------
// points [B,64,N] fp32 -> ptsTh [B,N,64] bf16 (tiled via LDS)
// ---------------------------------------------------------------------------
__global__ void transpose_pts(const float* __restrict__ pts,
                              unsigned short* __restrict__ ptsTh) {
    __shared__ float t[64][65];
    int b = blockIdx.y;
    int n0 = blockIdx.x * 64;
    int tx = threadIdx.x, ty = threadIdx.y;
    for (int c = ty; c < 64; c += 4)
        t[c][tx] = pts[((size_t)b * DFEAT + c) * NPTS + n0 + tx];
    __syncthreads();
    for (int r = ty; r < 64; r += 4)
        ptsTh[((size_t)b * NPTS + n0 + r) * DFEAT + tx] = f2b(t[tx][r]);
}

// ---------------------------------------------------------------------------
// Pack weights into MFMA B-fragment order (bf16). Unchanged from R6.
// ---------------------------------------------------------------------------
__global__ void pack_w(const float* __restrict__ w0, const float* __restrict__ w1,
                       const float* __restrict__ w2, unsigned short* __restrict__ wp) {
    int t = blockIdx.x, l = threadIdx.x;
    int kq = (l >> 4) * 8, n16 = l & 15;
    unsigned short o[8];
#pragma unroll
    for (int j = 0; j < 8; j++) {
        float v;
        if (t < 12) {
            int kt = t >> 2, nt = t & 3;
            int k = kt * 32 + kq + j, n = nt * 16 + n16;
            v = (k < 64) ? w0[n * INCH + 3 + k] : (k < 67 ? w0[n * INCH + (k - 64)] : 0.0f);
        } else if (t < 20) {
            int tt = t - 12, kt = tt >> 2, nt = tt & 3;
            v = w1[(nt * 16 + n16) * 64 + kt * 32 + kq + j];
        } else {
            int tt = t - 20, kt = tt >> 3, nt = tt & 7;
            v = w2[(nt * 16 + n16) * 64 + kt * 32 + kq + j];
        }
        o[j] = f2b(v);
    }
    *(v8s*)&wp[(size_t)t * 512 + l * 8] = *(v8s*)o;
}

// ---------------------------------------------------------------------------
// Ball query + MFMA MLP + max (unchanged from R6, verified absmax 0.0156).
// ---------------------------------------------------------------------------
__global__ __launch_bounds__(64, 2) void ball_mlp_mfma(
    const float* __restrict__ xyz,
    const unsigned short* __restrict__ ptsTh,
    const unsigned short* __restrict__ wp,
    const float* __restrict__ b0, const float* __restrict__ b1,
    const float* __restrict__ b2,
    const float* __restrict__ out0,
    float* __restrict__ out1)
{
    const float R2 = (float)(0.4 * 0.4);   // 0x3E23D70A — NOT 0.4f*0.4f
    int q = blockIdx.x;
    int b = q >> 9;
    int sg = q & 511;
    int lane = threadIdx.x;
    int col = lane & 15, quad = lane >> 4, kq = quad * 8;

    const float* xb = xyz + (size_t)b * 3 * NPTS;
    float qx = out0[(size_t)b * 3 * S_TOT + sg];
    float qy = out0[(size_t)b * 3 * S_TOT + S_TOT + sg];
    float qz = out0[(size_t)b * 3 * S_TOT + 2 * S_TOT + sg];

    __shared__ int s_idx[NSAMP];
    __shared__ short sX1[64 * 104];
    __shared__ short sX2[64 * 72];

    int cnt = 0;
#pragma unroll 4
    for (int base = 0; base < NPTS; base += 64) {
        int n = base + lane;
        float d2 = d2_exact(qx, qy, qz, xb[n], xb[NPTS + n], xb[2 * NPTS + n]);
        bool flag = d2 < R2;
        unsigned long long m = __ballot(flag);
        int pos = cnt + (int)__popcll(m & ((1ull << lane) - 1ull));
        if (flag && pos < NSAMP) s_idx[pos] = n;
        cnt += (int)__popcll(m);
    }
    if (cnt > NSAMP) cnt = NSAMP;

    int nb = (lane < cnt) ? s_idx[lane] : -1;
    float nx_ = 0.f, ny_ = 0.f, nz_ = 0.f;
    if (nb >= 0) { nx_ = xb[nb]; ny_ = xb[NPTS + nb]; nz_ = xb[2 * NPTS + nb]; }
    float fx = nx_ - qx, fy = ny_ - qy, fz = nz_ - qz;   // pad rows: -new_xyz
    int row = (nb < 0) ? (NPTS - 1) : nb;                // torch -1 wraps to last

    {
        const unsigned short* ph = ptsTh + ((size_t)b * NPTS + row) * DFEAT;
        short* xr = &sX1[lane * 104];
#pragma unroll
        for (int i = 0; i < 8; i++)
            *(v8s*)(xr + i * 8) = *(const v8s*)(ph + i * 8);
#pragma unroll
        for (int i = 0; i < 5; i++)
            *(v8s*)(xr + 64 + i * 8) = (v8s)0;
        v4s xyzp;
        xyzp[0] = (short)f2b(fx); xyzp[1] = (short)f2b(fy);
        xyzp[2] = (short)f2b(fz); xyzp[3] = 0;
        *(v4s*)(xr + 64) = xyzp;
    }

    const v8s* wpv = (const v8s*)wp;

    v4f acc[4][4];
#pragma unroll
    for (int nt = 0; nt < 4; nt++) {
        float bb = b0[nt * 16 + col];
#pragma unroll
        for (int mt = 0; mt < 4; mt++) acc[mt][nt] = (v4f){bb, bb, bb, bb};
    }
#pragma unroll
    for (int kt = 0; kt < 3; kt++) {
        v8s bf[4];
#pragma unroll
        for (int nt = 0; nt < 4; nt++) bf[nt] = wpv[(kt * 4 + nt) * 64 + lane];
#pragma unroll
        for (int mt = 0; mt < 4; mt++) {
            v8s a = *(const v8s*)&sX1[(mt * 16 + col) * 104 + kt * 32 + kq];
#pragma unroll
            for (int nt = 0; nt < 4; nt++)
                acc[mt][nt] = __builtin_amdgcn_mfma_f32_16x16x32_bf16(a, bf[nt], acc[mt][nt], 0, 0, 0);
        }
    }
#pragma unroll
    for (int mt = 0; mt < 4; mt++)
#pragma unroll
        for (int nt = 0; nt < 4; nt++)
#pragma unroll
            for (int r = 0; r < 4; r++)
                sX2[(mt * 16 + quad * 4 + r) * 72 + nt * 16 + col] =
                    (short)f2b(fmaxf(acc[mt][nt][r], 0.0f));

#pragma unroll
    for (int nt = 0; nt < 4; nt++) {
        float bb = b1[nt * 16 + col];
#pragma unroll
        for (int mt = 0; mt < 4; mt++) acc[mt][nt] = (v4f){bb, bb, bb, bb};
    }
#pragma unroll
    for (int kt = 0; kt < 2; kt++) {
        v8s bf[4];
#pragma unroll
        for (int nt = 0; nt < 4; nt++) bf[nt] = wpv[(12 + kt * 4 + nt) * 64 + lane];
#pragma unroll
        for (int mt = 0; mt < 4; mt++) {
            v8s a = *(const v8s*)&sX2[(mt * 16 + col) * 72 + kt * 32 + kq];
#pragma unroll
            for (int nt = 0; nt < 4; nt++)
                acc[mt][nt] = __builtin_amdgcn_mfma_f32_16x16x32_bf16(a, bf[nt], acc[mt][nt], 0, 0, 0);
        }
    }
#pragma unroll
    for (int mt = 0; mt < 4; mt++)
#pragma unroll
        for (int nt = 0; nt < 4; nt++)
#pragma unroll
            for (int r = 0; r < 4; r++)
                sX1[(mt * 16 + quad * 4 + r) * 72 + nt * 16 + col] =
                    (short)f2b(fmaxf(acc[mt][nt][r], 0.0f));

#pragma unroll
    for (int p = 0; p < 2; p++) {
#pragma unroll
        for (int nt = 0; nt < 4; nt++) {
            float bb = b2[(p * 4 + nt) * 16 + col];
#pragma unroll
            for (int mt = 0; mt < 4; mt++) acc[mt][nt] = (v4f){bb, bb, bb, bb};
        }
#pragma unroll
        for (int kt = 0; kt < 2; kt++) {
            v8s bf[4];
#pragma unroll
            for (int nt = 0; nt < 4; nt++)
                bf[nt] = wpv[(20 + kt * 8 + p * 4 + nt) * 64 + lane];
#pragma unroll
            for (int mt = 0; mt < 4; mt++) {
                v8s a = *(const v8s*)&sX1[(mt * 16 + col) * 72 + kt * 32 + kq];
#pragma unroll
                for (int nt = 0; nt < 4; nt++)
                    acc[mt][nt] = __builtin_amdgcn_mfma_f32_16x16x32_bf16(a, bf[nt], acc[mt][nt], 0, 0, 0);
            }
        }
#pragma unroll
        for (int nt = 0; nt < 4; nt++) {
            float v = 0.0f;
#pragma unroll
            for (int mt = 0; mt < 4; mt++)
#pragma unroll
                for (int r = 0; r < 4; r++)
                    v = fmaxf(v, acc[mt][nt][r]);
            v = fmaxf(v, __shfl_xor(v, 16));
            v = fmaxf(v, __shfl_xor(v, 32));
            if (lane < 16)
                out1[((size_t)(b * 128 + (p * 4 + nt) * 16 + lane)) * S_TOT + sg] = v;
        }
    }
}

// ---------------------------------------------------------------------------
// Fallback ball+MLP (no ws): unchanged from R6.
// ---------------------------------------------------------------------------
__global__ __launch_bounds__(64, 1) void ball_mlp_fb(
    const float* __restrict__ xyz, const float* __restrict__ pts,
    const float* __restrict__ w0, const float* __restrict__ b0,
    const float* __restrict__ w1, const float* __restrict__ b1,
    const float* __restrict__ w2, const float* __restrict__ b2,
    const float* __restrict__ out0, float* __restrict__ out1)
{
    const float R2 = (float)(0.4 * 0.4);
    int q = blockIdx.x;
    int b = q >> 9, sg = q & 511, lane = threadIdx.x;
    const float* xb = xyz + (size_t)b * 3 * NPTS;
    float qx = out0[(size_t)b * 3 * S_TOT + sg];
    float qy = out0[(size_t)b * 3 * S_TOT + S_TOT + sg];
    float qz = out0[(size_t)b * 3 * S_TOT + 2 * S_TOT + sg];

    __shared__ int s_idx[NSAMP];
    __shared__ float s_h[32 * 64];
    int cnt = 0;
    for (int base = 0; base < NPTS; base += 64) {
        int n = base + lane;
        float d2 = d2_exact(qx, qy, qz, xb[n], xb[NPTS + n], xb[2 * NPTS + n]);
        bool flag = d2 < R2;
        unsigned long long m = __ballot(flag);
        int pos = cnt + (int)__popcll(m & ((1ull << lane) - 1ull));
        if (flag && pos < NSAMP) s_idx[pos] = n;
        cnt += (int)__popcll(m);
    }
    if (cnt > NSAMP) cnt = NSAMP;
    int nb = (lane < cnt) ? s_idx[lane] : -1;
    float nx_ = 0.f, ny_ = 0.f, nz_ = 0.f;
    if (nb >= 0) { nx_ = xb[nb]; ny_ = xb[NPTS + nb]; nz_ = xb[2 * NPTS + nb]; }
    float fx = nx_ - qx, fy = ny_ - qy, fz = nz_ - qz;
    int row = (nb < 0) ? (NPTS - 1) : nb;

    float h1[64];
#pragma unroll
    for (int o = 0; o < 64; o++) {
        float a = __builtin_fmaf(w0[o * INCH + 0], fx, b0[o]);
        a = __builtin_fmaf(w0[o * INCH + 1], fy, a);
        h1[o] = __builtin_fmaf(w0[o * INCH + 2], fz, a);
    }
    const float* pb = pts + (size_t)b * DFEAT * NPTS + row;
#pragma unroll 1
    for (int c = 0; c < 64; c++) {
        float f = pb[(size_t)c * NPTS];
#pragma unroll
        for (int o = 0; o < 64; o++)
            h1[o] = __builtin_fmaf(w0[o * INCH + 3 + c], f, h1[o]);
    }
#pragma unroll
    for (int c = 0; c < 32; c++) s_h[c * 64 + lane] = fmaxf(h1[c], 0.0f);
    float h1h[32];
#pragma unroll
    for (int c = 0; c < 32; c++) h1h[c] = fmaxf(h1[32 + c], 0.0f);

    float h2[64];
#pragma unroll
    for (int o = 0; o < 64; o++) h2[o] = b1[o];
#pragma unroll 1
    for (int c = 0; c < 32; c++) {
        float hc = s_h[c * 64 + lane];
#pragma unroll
        for (int o = 0; o < 64; o++)
            h2[o] = __builtin_fmaf(w1[o * 64 + c], hc, h2[o]);
    }
#pragma unroll
    for (int c = 0; c < 32; c++) s_h[c * 64 + lane] = h1h[c];
#pragma unroll 1
    for (int c = 0; c < 32; c++) {
        float hc = s_h[c * 64 + lane];
#pragma unroll
        for (int o = 0; o < 64; o++)
            h2[o] = __builtin_fmaf(w1[o * 64 + (32 + c)], hc, h2[o]);
    }
#pragma unroll
    for (int o = 0; o < 64; o++) h2[o] = fmaxf(h2[o], 0.0f);

#pragma unroll 2
    for (int o = 0; o < 128; o++) {
        const float* wr = w2 + o * 64;
        float acc = b2[o];
#pragma unroll
        for (int c = 0; c < 64; c++) acc = __builtin_fmaf(wr[c], h2[c], acc);
        acc = fmaxf(acc, 0.0f);
#pragma unroll
        for (int off = 32; off >= 1; off >>= 1)
            acc = fmaxf(acc, __shfl_down(acc, off));
        if (lane == 0) out1[((size_t)(b * 128 + o)) * S_TOT + sg] = acc;
    }
}

extern "C" void kernel_launch(void* const* d_in, const int* in_sizes, int n_in,
                              void* d_out, int out_size, void* d_ws, size_t ws_size,
                              hipStream_t stream) {
    const float* xyz  = (const float*)d_in[0];
    const float* pts  = (const float*)d_in[1];
    const float* attn = (const float*)d_in[2];
    const float* w0 = (const float*)d_in[3];
    const float* b0 = (const float*)d_in[4];
    const float* w1 = (const float*)d_in[5];
    const float* b1 = (const float*)d_in[6];
    const float* w2 = (const float*)d_in[7];
    const float* b2 = (const float*)d_in[8];

    float* out0 = (float*)d_out;                    // [B,3,S]
    float* out1 = out0 + (size_t)NB * 3 * S_TOT;    // [B,128,S]
    float* out2 = out1 + (size_t)NB * 128 * S_TOT;  // [B,1,S]

    // ws: wp (36 tiles * 1KB) | ptsTh bf16 [B][N][64] | cxyz | hdr
    unsigned short* wp    = (unsigned short*)d_ws;
    unsigned short* ptsTh = (unsigned short*)((char*)d_ws + 36864);
    float4*         cxyz  = (float4*)((char*)d_ws + 36864 + 8388608);
    int*            hdr   = (int*)((char*)cxyz + (size_t)16 * CCAP * 16);
    const size_t need = 36864 + 8388608 + (size_t)16 * CCAP * 16 + 128;

    if (ws_size >= need) {
        fps_compact<<<16, 1024, 0, stream>>>(xyz, attn, cxyz, hdr);
        fps_iter<<<16, 256, 0, stream>>>(attn, cxyz, hdr, out0, out2);
        fps_kernel<<<16, 1024, 0, stream>>>(xyz, attn, hdr, out0, out2);  // gated
        transpose_pts<<<dim3(NPTS / 64, NB), dim3(64, 4), 0, stream>>>(pts, ptsTh);
        pack_w<<<36, 64, 0, stream>>>(w0, w1, w2, wp);
        ball_mlp_mfma<<<NB * S_TOT, 64, 0, stream>>>(xyz, ptsTh, wp, b0, b1, b2,
                                                     out0, out1);
    } else {
        fps_kernel<<<16, 1024, 0, stream>>>(xyz, attn, nullptr, out0, out2);
        ball_mlp_fb<<<NB * S_TOT, 64, 0, stream>>>(xyz, pts, w0, b0, w1, b1,
                                                   w2, b2, out0, out1);
    }
}